// Round 5
// baseline (268.324 us; speedup 1.0000x reference)
//
#include <hip/hip_runtime.h>
#include <math.h>

#define N_NODES 30000
#define N_EDGES 480000
#define DIM     128
#define EPSV    1e-5f

typedef short short8 __attribute__((ext_vector_type(8)));
typedef float float4v __attribute__((ext_vector_type(4)));

__device__ __forceinline__ unsigned short f2bf(float f) {   // RTN f32->bf16
    unsigned u = __float_as_uint(f);
    u += 0x7FFFu + ((u >> 16) & 1u);
    return (unsigned short)(u >> 16);
}
__device__ __forceinline__ float bf2f(unsigned short u) {
    return __uint_as_float(((unsigned)u) << 16);
}

// ---------------- split h,W into bf16 hi/lo; zero counts/redbuf/zmax ----------
__global__ __launch_bounds__(256) void convert_kernel(const float* __restrict__ h,
                                                      const float* __restrict__ W,
                                                      unsigned short* __restrict__ hh,
                                                      unsigned short* __restrict__ hl,
                                                      unsigned short* __restrict__ wh,
                                                      unsigned short* __restrict__ wl,
                                                      int* __restrict__ counts,
                                                      float* __restrict__ redbuf,
                                                      int* __restrict__ zmax) {
    int i = blockIdx.x * 256 + threadIdx.x;        // grid = 3766 exact (964096 threads)
    const float* srcp; unsigned short *dh, *dl; int base;
    if (i < 960000) { srcp = h; dh = hh; dl = hl; base = i * 4; }
    else            { srcp = W; dh = wh; dl = wl; base = (i - 960000) * 4; }
    float4 v = *reinterpret_cast<const float4*>(srcp + base);
    ushort4 hi, lo;
    hi.x = f2bf(v.x); lo.x = f2bf(v.x - bf2f(hi.x));
    hi.y = f2bf(v.y); lo.y = f2bf(v.y - bf2f(hi.y));
    hi.z = f2bf(v.z); lo.z = f2bf(v.z - bf2f(hi.z));
    hi.w = f2bf(v.w); lo.w = f2bf(v.w - bf2f(hi.w));
    *reinterpret_cast<ushort4*>(dh + base) = hi;
    *reinterpret_cast<ushort4*>(dl + base) = lo;
    if (i < N_NODES) counts[i] = 0;
    if (i < 2 * DIM) redbuf[i] = 0.0f;
    if (i == 0) zmax[0] = 0;
}

// ---------------- CSR build ----------------
__global__ void count_kernel(const int* __restrict__ dst, int* __restrict__ counts) {
    int i = blockIdx.x * blockDim.x + threadIdx.x;
    if (i < N_EDGES) atomicAdd(&counts[dst[i]], 1);
}

__global__ __launch_bounds__(1024) void scan_kernel(const int* __restrict__ counts,
                                                    int* __restrict__ offsets,
                                                    int* __restrict__ cursor) {
    __shared__ int wavebuf[16];
    __shared__ int tilebase;
    __shared__ int tiletotal;
    int tid = threadIdx.x;
    int lane = tid & 63, wv = tid >> 6;
    if (tid == 0) tilebase = 0;
    __syncthreads();
    for (int base = 0; base < N_NODES; base += 1024) {
        int i = base + tid;
        int v = (i < N_NODES) ? counts[i] : 0;
        int sc = v;
        #pragma unroll
        for (int off = 1; off < 64; off <<= 1) {
            int t = __shfl_up(sc, off);
            if (lane >= off) sc += t;
        }
        if (lane == 63) wavebuf[wv] = sc;
        __syncthreads();
        if (wv == 0) {
            int wval = (lane < 16) ? wavebuf[lane] : 0;
            int wsc = wval;
            #pragma unroll
            for (int off = 1; off < 16; off <<= 1) {
                int t = __shfl_up(wsc, off);
                if (lane >= off) wsc += t;
            }
            if (lane < 16) wavebuf[lane] = wsc - wval;
            if (lane == 15) tiletotal = wsc;
        }
        __syncthreads();
        int excl = (sc - v) + wavebuf[wv] + tilebase;
        if (i < N_NODES) { offsets[i] = excl; cursor[i] = excl; }
        __syncthreads();
        if (tid == 0) tilebase += tiletotal;
        __syncthreads();
    }
    if (tid == 0) offsets[N_NODES] = tilebase;
}

__global__ void fill_kernel(const int* __restrict__ src, const int* __restrict__ dst,
                            int* __restrict__ cursor, int* __restrict__ edge_src) {
    int i = blockIdx.x * blockDim.x + threadIdx.x;
    if (i < N_EDGES) {
        int p = atomicAdd(&cursor[dst[i]], 1);
        edge_src[p] = src[i];
    }
}

// ---------------- z = h @ W^T via bf16-split MFMA (3 products, no LDS) --------
// wave per 16-row tile x full N=128. A frag: lane holds h[row0+(lane&15)][kq+j],
// kq=(lane>>4)*8. B frag (B^T pattern): lane holds W[n*16+(lane&15)][kq+j].
// C/D: row=(lane>>4)*4+reg, col=lane&15 (m89-verified).
__global__ __launch_bounds__(256) void gemm_kernel(const unsigned short* __restrict__ hh,
                                                   const unsigned short* __restrict__ hl,
                                                   const unsigned short* __restrict__ wh,
                                                   const unsigned short* __restrict__ wl,
                                                   float* __restrict__ z,
                                                   unsigned short* __restrict__ z2,
                                                   int* __restrict__ zmax) {
    int t = threadIdx.x;
    int wv = t >> 6, lane = t & 63;
    int tile = blockIdx.x * 4 + wv;            // grid 469 -> tiles 0..1875 (1875 = dup)
    int row0 = tile * 16;
    int m = lane & 15;
    int kq = (lane >> 4) * 8;
    int rowA = row0 + m; if (rowA > N_NODES - 1) rowA = N_NODES - 1;
    short8 ah[4], al[4];
    #pragma unroll
    for (int ks = 0; ks < 4; ++ks) {
        ah[ks] = *reinterpret_cast<const short8*>(hh + (size_t)rowA * DIM + ks * 32 + kq);
        al[ks] = *reinterpret_cast<const short8*>(hl + (size_t)rowA * DIM + ks * 32 + kq);
    }
    float4v acc[8];
    #pragma unroll
    for (int n = 0; n < 8; ++n) acc[n] = (float4v){0.f, 0.f, 0.f, 0.f};
    #pragma unroll
    for (int n = 0; n < 8; ++n) {
        #pragma unroll
        for (int ks = 0; ks < 4; ++ks) {
            size_t boff = (size_t)(n * 16 + m) * DIM + ks * 32 + kq;
            short8 bh = *reinterpret_cast<const short8*>(wh + boff);
            short8 bl = *reinterpret_cast<const short8*>(wl + boff);
            acc[n] = __builtin_amdgcn_mfma_f32_16x16x32_bf16(al[ks], bh, acc[n], 0, 0, 0);
            acc[n] = __builtin_amdgcn_mfma_f32_16x16x32_bf16(ah[ks], bl, acc[n], 0, 0, 0);
            acc[n] = __builtin_amdgcn_mfma_f32_16x16x32_bf16(ah[ks], bh, acc[n], 0, 0, 0);
        }
    }
    int crow = (lane >> 4) * 4;
    int ccol = lane & 15;
    float amax = 0.f;
    #pragma unroll
    for (int n = 0; n < 8; ++n) {
        #pragma unroll
        for (int r = 0; r < 4; ++r) {
            int row = row0 + crow + r;
            int col = n * 16 + ccol;
            float v = acc[n][r];
            amax = fmaxf(amax, fabsf(v));
            if (row < N_NODES) {
                z[(size_t)row * DIM + col] = v;
                _Float16 hv = (_Float16)v;
                z2[(size_t)row * DIM + col] = *reinterpret_cast<unsigned short*>(&hv);
            }
        }
    }
    #pragma unroll
    for (int off = 32; off > 0; off >>= 1)
        amax = fmaxf(amax, __shfl_down(amax, off));
    if (lane == 0) atomicMax(zmax, __float_as_int(amax));
}

// ---------------- per-node softmax-aggregate (offset trick) ----------------
__global__ __launch_bounds__(256) void node_kernel(const float* __restrict__ z,
                                                   const unsigned short* __restrict__ z2,
                                                   const int* __restrict__ offsets,
                                                   const int* __restrict__ edge_src,
                                                   const float* __restrict__ snorm,
                                                   const int* __restrict__ zmax,
                                                   float* __restrict__ hout) {
    int tid = threadIdx.x;
    int lane = tid & 63;
    int node = blockIdx.x * 4 + (tid >> 6);   // grid = 7500 exact
    float Mg = __int_as_float(zmax[0]);
    const float2* zp = reinterpret_cast<const float2*>(z);
    float2 zd = zp[(size_t)node * 64 + lane];
    float m0 = fabsf(zd.x) * Mg, m1 = fabsf(zd.y) * Mg;
    int start = offsets[node], end = offsets[node + 1];
    float s0 = 0.f, s1 = 0.f, w0 = 0.f, w1 = 0.f;
    for (int base = start; base < end; base += 64) {
        int cnt = min(64, end - base);
        int es = (base + lane < end) ? edge_src[base + lane] : 0;
        for (int j = 0; j < cnt; ++j) {
            int sn = __builtin_amdgcn_readlane(es, j);
            unsigned v = *reinterpret_cast<const unsigned*>(z2 + (size_t)sn * DIM + lane * 2);
            union { unsigned u; _Float16 f[2]; } cv; cv.u = v;
            float zs0 = (float)cv.f[0], zs1 = (float)cv.f[1];
            float p0 = __expf(fmaf(zs0, zd.x, -m0));
            float p1 = __expf(fmaf(zs1, zd.y, -m1));
            s0 += p0; w0 = fmaf(p0, zs0, w0);
            s1 += p1; w1 = fmaf(p1, zs1, w1);
        }
    }
    float snv = snorm[node];
    float2 o;
    o.x = (s0 > 0.f) ? (w0 / s0) * snv : 0.f;
    o.y = (s1 > 0.f) ? (w1 / s1) * snv : 0.f;
    reinterpret_cast<float2*>(hout)[(size_t)node * 64 + lane] = o;
}

// ---------------- batch-norm statistics ----------------
__global__ __launch_bounds__(256) void reduce_kernel(const float* __restrict__ hout,
                                                     float* __restrict__ redbuf) {
    __shared__ float lsum[256], lsq[256];
    int tid = threadIdx.x;
    int c = tid & 127;
    int half = tid >> 7;
    int rbeg = blockIdx.x * 150;              // grid = 200 exact
    float s = 0.f, q = 0.f;
    for (int r = rbeg + half; r < rbeg + 150; r += 2) {
        float v = hout[(size_t)r * DIM + c];
        s += v; q += v * v;
    }
    lsum[tid] = s; lsq[tid] = q;
    __syncthreads();
    if (tid < 128) {
        s = lsum[tid] + lsum[tid + 128];
        q = lsq[tid] + lsq[tid + 128];
        atomicAdd(&redbuf[c], s);
        atomicAdd(&redbuf[DIM + c], q);
    }
}

__global__ void finalize_kernel(const float* __restrict__ redbuf,
                                const float* __restrict__ gamma,
                                const float* __restrict__ beta,
                                float* __restrict__ params) {
    int c = threadIdx.x;   // 128 threads
    float mu = redbuf[c] * (1.0f / N_NODES);
    float var = redbuf[DIM + c] * (1.0f / N_NODES) - mu * mu;
    float scale = gamma[c] * rsqrtf(var + EPSV);
    params[c] = scale;
    params[DIM + c] = beta[c] - mu * scale;
}

// ---------------- fused BN + ELU + fp32 store ----------------
__global__ __launch_bounds__(256) void elu_kernel(const float* __restrict__ hout,
                                                  const float* __restrict__ params,
                                                  float* __restrict__ out) {
    int idx = (blockIdx.x * 256 + threadIdx.x) * 4;   // grid = 3750 exact
    int c = idx & 127;
    float4 v = reinterpret_cast<const float4*>(hout)[idx >> 2];
    float4 o;
    {
        float y = v.x * params[c + 0] + params[DIM + c + 0];
        o.x = (y > 0.f) ? y : expm1f(y);
        y = v.y * params[c + 1] + params[DIM + c + 1];
        o.y = (y > 0.f) ? y : expm1f(y);
        y = v.z * params[c + 2] + params[DIM + c + 2];
        o.z = (y > 0.f) ? y : expm1f(y);
        y = v.w * params[c + 3] + params[DIM + c + 3];
        o.w = (y > 0.f) ? y : expm1f(y);
    }
    reinterpret_cast<float4*>(out)[idx >> 2] = o;
}

extern "C" void kernel_launch(void* const* d_in, const int* in_sizes, int n_in,
                              void* d_out, int out_size, void* d_ws, size_t ws_size,
                              hipStream_t stream) {
    const float* h     = (const float*)d_in[0];
    const float* snorm = (const float*)d_in[1];
    const float* W     = (const float*)d_in[2];
    const float* gamma = (const float*)d_in[3];
    const float* beta  = (const float*)d_in[4];
    const int*   src   = (const int*)d_in[5];
    const int*   dst   = (const int*)d_in[6];
    float*       out   = (float*)d_out;

    char* ws = (char*)d_ws;
    float*          zbuf     = (float*)         (ws + 0);          // z, later hout (15,360,000 B)
    unsigned short* z2       = (unsigned short*)(ws + 15360000);   //  7,680,000 B (fp16 z)
    unsigned short* hh       = (unsigned short*)(ws + 23040000);   //  7,680,000 B
    unsigned short* hl       = (unsigned short*)(ws + 30720000);   //  7,680,000 B
    unsigned short* wh2      = (unsigned short*)(ws + 38400000);   //     32,768 B
    unsigned short* wl2      = (unsigned short*)(ws + 38432768);   //     32,768 B
    int*            counts   = (int*)           (ws + 38465536);   //    120,000 B
    int*            offsets  = (int*)           (ws + 38585536);   //    120,004 B
    int*            cursor   = (int*)           (ws + 38705552);   //    120,000 B
    int*            edge_src = (int*)           (ws + 38825552);   //  1,920,000 B
    float*          redbuf   = (float*)         (ws + 40745552);   //      1,024 B
    float*          params   = (float*)         (ws + 40746576);   //      1,024 B
    int*            zmax     = (int*)           (ws + 40747600);   //          4 B

    convert_kernel<<<3766, 256, 0, stream>>>(h, W, hh, hl, wh2, wl2, counts, redbuf, zmax);
    count_kernel<<<(N_EDGES + 255) / 256, 256, 0, stream>>>(dst, counts);
    scan_kernel<<<1, 1024, 0, stream>>>(counts, offsets, cursor);
    fill_kernel<<<(N_EDGES + 255) / 256, 256, 0, stream>>>(src, dst, cursor, edge_src);
    gemm_kernel<<<469, 256, 0, stream>>>(hh, hl, wh2, wl2, zbuf, z2, zmax);
    node_kernel<<<N_NODES / 4, 256, 0, stream>>>(zbuf, z2, offsets, edge_src, snorm, zmax, zbuf);
    reduce_kernel<<<200, 256, 0, stream>>>(zbuf, redbuf);
    finalize_kernel<<<1, 128, 0, stream>>>(redbuf, gamma, beta, params);
    elu_kernel<<<(N_NODES * DIM) / 1024, 256, 0, stream>>>(zbuf, params, out);
}

// Round 6
// 216.586 us; speedup vs baseline: 1.2389x; 1.2389x over previous
//
#include <hip/hip_runtime.h>
#include <math.h>

#define N_NODES 30000
#define N_EDGES 480000
#define DIM     128
#define EPSV    1e-5f

typedef short short8 __attribute__((ext_vector_type(8)));
typedef float float4v __attribute__((ext_vector_type(4)));

__device__ __forceinline__ unsigned short f2bf(float f) {   // RTN f32->bf16
    unsigned u = __float_as_uint(f);
    u += 0x7FFFu + ((u >> 16) & 1u);
    return (unsigned short)(u >> 16);
}
__device__ __forceinline__ float bf2f(unsigned short u) {
    return __uint_as_float(((unsigned)u) << 16);
}

// ---------------- split h,W into bf16 hi/lo; zero counts/redbuf/zmax ----------
__global__ __launch_bounds__(256) void convert_kernel(const float* __restrict__ h,
                                                      const float* __restrict__ W,
                                                      unsigned short* __restrict__ hh,
                                                      unsigned short* __restrict__ hl,
                                                      unsigned short* __restrict__ wh,
                                                      unsigned short* __restrict__ wl,
                                                      int* __restrict__ counts,
                                                      float* __restrict__ redbuf,
                                                      int* __restrict__ zmax) {
    int i = blockIdx.x * 256 + threadIdx.x;        // grid = 3766 exact (964096 threads)
    const float* srcp; unsigned short *dh, *dl; int base;
    if (i < 960000) { srcp = h; dh = hh; dl = hl; base = i * 4; }
    else            { srcp = W; dh = wh; dl = wl; base = (i - 960000) * 4; }
    float4 v = *reinterpret_cast<const float4*>(srcp + base);
    ushort4 hi, lo;
    hi.x = f2bf(v.x); lo.x = f2bf(v.x - bf2f(hi.x));
    hi.y = f2bf(v.y); lo.y = f2bf(v.y - bf2f(hi.y));
    hi.z = f2bf(v.z); lo.z = f2bf(v.z - bf2f(hi.z));
    hi.w = f2bf(v.w); lo.w = f2bf(v.w - bf2f(hi.w));
    *reinterpret_cast<ushort4*>(dh + base) = hi;
    *reinterpret_cast<ushort4*>(dl + base) = lo;
    if (i < N_NODES) counts[i] = 0;
    if (i < 2 * DIM) redbuf[i] = 0.0f;
    if (i == 0) zmax[0] = 0;
}

// ---------------- CSR build ----------------
__global__ void count_kernel(const int* __restrict__ dst, int* __restrict__ counts) {
    int i = blockIdx.x * blockDim.x + threadIdx.x;
    if (i < N_EDGES) atomicAdd(&counts[dst[i]], 1);
}

// parallel scan, stage 1: per-block (256-wide) exclusive scan + block total
__global__ __launch_bounds__(256) void scan1_kernel(const int* __restrict__ counts,
                                                    int* __restrict__ offsets,
                                                    int* __restrict__ partials) {
    __shared__ int wtot[4];
    __shared__ int btot;
    int t = threadIdx.x;
    int lane = t & 63, wv = t >> 6;
    int i = blockIdx.x * 256 + t;                  // grid = 118
    int v = (i < N_NODES) ? counts[i] : 0;
    int sc = v;
    #pragma unroll
    for (int off = 1; off < 64; off <<= 1) {
        int x = __shfl_up(sc, off);
        if (lane >= off) sc += x;
    }
    if (lane == 63) wtot[wv] = sc;
    __syncthreads();
    if (t == 0) {
        int run = 0;
        #pragma unroll
        for (int w = 0; w < 4; ++w) { int x = wtot[w]; wtot[w] = run; run += x; }
        btot = run;
    }
    __syncthreads();
    if (i < N_NODES) offsets[i] = (sc - v) + wtot[wv];
    if (t == 0) partials[blockIdx.x] = btot;
}

// stage 2: one wave scans the 118 block totals (exclusive); ps[118] = grand total
__global__ __launch_bounds__(64) void scan2_kernel(const int* __restrict__ partials,
                                                   int* __restrict__ ps) {
    int t = threadIdx.x;                            // 64 threads, each owns 2 slots
    int a = (2 * t     < 118) ? partials[2 * t]     : 0;
    int b = (2 * t + 1 < 118) ? partials[2 * t + 1] : 0;
    int pair = a + b;
    int sc = pair;
    #pragma unroll
    for (int off = 1; off < 64; off <<= 1) {
        int x = __shfl_up(sc, off);
        if (t >= off) sc += x;
    }
    int base = sc - pair;
    if (2 * t     < 118) ps[2 * t]     = base;
    if (2 * t + 1 < 118) ps[2 * t + 1] = base + a;
    if (t == 63) ps[118] = sc;                      // grand total
}

// stage 3: add block bases; init cursor; write offsets[N]
__global__ __launch_bounds__(256) void scan3_kernel(int* __restrict__ offsets,
                                                    const int* __restrict__ ps,
                                                    int* __restrict__ cursor) {
    int i = blockIdx.x * 256 + threadIdx.x;        // grid = 118
    if (i < N_NODES) {
        int v = offsets[i] + ps[i >> 8];
        offsets[i] = v;
        cursor[i] = v;
    }
    if (i == 0) offsets[N_NODES] = ps[118];
}

__global__ void fill_kernel(const int* __restrict__ src, const int* __restrict__ dst,
                            int* __restrict__ cursor, int* __restrict__ edge_src) {
    int i = blockIdx.x * blockDim.x + threadIdx.x;
    if (i < N_EDGES) {
        int p = atomicAdd(&cursor[dst[i]], 1);
        edge_src[p] = src[i];
    }
}

// ---------------- z = h @ W^T via bf16-split MFMA, W staged in LDS ------------
// Block = 4 waves x 2 A-tiles each (8 tiles/block, grid 235). W hi/lo staged in
// LDS pre-swizzled to fragment order: chunk[(n*4+ks)*64 + lane] = 8 shorts, so
// ds_read_b128 is uniform-base + lane*16 (conflict-free). Each B fragment feeds
// 2 A-tiles (6 MFMAs per ds_read pair).
__global__ __launch_bounds__(256) void gemm_kernel(const unsigned short* __restrict__ hh,
                                                   const unsigned short* __restrict__ hl,
                                                   const unsigned short* __restrict__ wh,
                                                   const unsigned short* __restrict__ wl,
                                                   float* __restrict__ z,
                                                   unsigned short* __restrict__ z2,
                                                   int* __restrict__ zmax) {
    __shared__ short bsh[16384];   // 32 KB
    __shared__ short bsl[16384];   // 32 KB
    int t = threadIdx.x;
    int wv = t >> 6, lane = t & 63;
    for (int i = t; i < 2048; i += 256) {          // stage + swizzle W
        int r = i >> 4;                            // 0..127 (= n*16+m)
        int c = i & 15;                            // 0..15  (= ks*4+q)
        int n = r >> 4, m = r & 15;
        int ks = c >> 2, q = c & 3;
        int cd = ((n * 4 + ks) * 64 + q * 16 + m) * 8;
        *reinterpret_cast<short8*>(&bsh[cd]) =
            *reinterpret_cast<const short8*>(wh + r * DIM + c * 8);
        *reinterpret_cast<short8*>(&bsl[cd]) =
            *reinterpret_cast<const short8*>(wl + r * DIM + c * 8);
    }
    int tile0 = blockIdx.x * 8 + wv * 2;           // grid 235 -> tiles 0..1879 (clamped dups)
    int m = lane & 15;
    int kq = (lane >> 4) * 8;
    short8 ah[2][4], al[2][4];
    #pragma unroll
    for (int tt = 0; tt < 2; ++tt) {
        int rowA = (tile0 + tt) * 16 + m;
        if (rowA > N_NODES - 1) rowA = N_NODES - 1;
        #pragma unroll
        for (int ks = 0; ks < 4; ++ks) {
            ah[tt][ks] = *reinterpret_cast<const short8*>(hh + (size_t)rowA * DIM + ks * 32 + kq);
            al[tt][ks] = *reinterpret_cast<const short8*>(hl + (size_t)rowA * DIM + ks * 32 + kq);
        }
    }
    float4v acc[2][8];
    #pragma unroll
    for (int tt = 0; tt < 2; ++tt)
        #pragma unroll
        for (int n = 0; n < 8; ++n) acc[tt][n] = (float4v){0.f, 0.f, 0.f, 0.f};
    __syncthreads();
    #pragma unroll
    for (int n = 0; n < 8; ++n) {
        #pragma unroll
        for (int ks = 0; ks < 4; ++ks) {
            int cd = ((n * 4 + ks) * 64 + lane) * 8;
            short8 bh = *reinterpret_cast<const short8*>(&bsh[cd]);
            short8 bl = *reinterpret_cast<const short8*>(&bsl[cd]);
            #pragma unroll
            for (int tt = 0; tt < 2; ++tt) {
                acc[tt][n] = __builtin_amdgcn_mfma_f32_16x16x32_bf16(al[tt][ks], bh, acc[tt][n], 0, 0, 0);
                acc[tt][n] = __builtin_amdgcn_mfma_f32_16x16x32_bf16(ah[tt][ks], bl, acc[tt][n], 0, 0, 0);
                acc[tt][n] = __builtin_amdgcn_mfma_f32_16x16x32_bf16(ah[tt][ks], bh, acc[tt][n], 0, 0, 0);
            }
        }
    }
    int crow = (lane >> 4) * 4;
    int ccol = lane & 15;
    float amax = 0.f;
    #pragma unroll
    for (int tt = 0; tt < 2; ++tt) {
        int row0 = (tile0 + tt) * 16;
        #pragma unroll
        for (int n = 0; n < 8; ++n) {
            #pragma unroll
            for (int r = 0; r < 4; ++r) {
                int row = row0 + crow + r;
                int col = n * 16 + ccol;
                float v = acc[tt][n][r];
                amax = fmaxf(amax, fabsf(v));
                if (row < N_NODES) {
                    z[(size_t)row * DIM + col] = v;
                    _Float16 hv = (_Float16)v;
                    z2[(size_t)row * DIM + col] = *reinterpret_cast<unsigned short*>(&hv);
                }
            }
        }
    }
    #pragma unroll
    for (int off = 32; off > 0; off >>= 1)
        amax = fmaxf(amax, __shfl_down(amax, off));
    if (lane == 0) atomicMax(zmax, __float_as_int(amax));
}

// ---------------- per-node softmax-aggregate (offset trick, 4x pipelined) -----
__global__ __launch_bounds__(256) void node_kernel(const float* __restrict__ z,
                                                   const unsigned short* __restrict__ z2,
                                                   const int* __restrict__ offsets,
                                                   const int* __restrict__ edge_src,
                                                   const float* __restrict__ snorm,
                                                   const int* __restrict__ zmax,
                                                   float* __restrict__ hout) {
    int tid = threadIdx.x;
    int lane = tid & 63;
    int node = blockIdx.x * 4 + (tid >> 6);   // grid = 7500 exact
    float Mg = __int_as_float(zmax[0]);
    const float2* zp = reinterpret_cast<const float2*>(z);
    float2 zd = zp[(size_t)node * 64 + lane];
    float m0 = fabsf(zd.x) * Mg, m1 = fabsf(zd.y) * Mg;
    int start = offsets[node], end = offsets[node + 1];
    float s0 = 0.f, s1 = 0.f, w0 = 0.f, w1 = 0.f;
    for (int base = start; base < end; base += 64) {
        int cnt = min(64, end - base);
        int es = (base + lane < end) ? edge_src[base + lane] : 0;
        int j = 0;
        for (; j + 3 < cnt; j += 4) {
            int sn0 = __builtin_amdgcn_readlane(es, j);
            int sn1 = __builtin_amdgcn_readlane(es, j + 1);
            int sn2 = __builtin_amdgcn_readlane(es, j + 2);
            int sn3 = __builtin_amdgcn_readlane(es, j + 3);
            unsigned v0 = *reinterpret_cast<const unsigned*>(z2 + (size_t)sn0 * DIM + lane * 2);
            unsigned v1 = *reinterpret_cast<const unsigned*>(z2 + (size_t)sn1 * DIM + lane * 2);
            unsigned v2 = *reinterpret_cast<const unsigned*>(z2 + (size_t)sn2 * DIM + lane * 2);
            unsigned v3 = *reinterpret_cast<const unsigned*>(z2 + (size_t)sn3 * DIM + lane * 2);
            union { unsigned u; _Float16 f[2]; } c0, c1, c2, c3;
            c0.u = v0; c1.u = v1; c2.u = v2; c3.u = v3;
            float a0 = (float)c0.f[0], b0 = (float)c0.f[1];
            float a1 = (float)c1.f[0], b1 = (float)c1.f[1];
            float a2 = (float)c2.f[0], b2 = (float)c2.f[1];
            float a3 = (float)c3.f[0], b3 = (float)c3.f[1];
            float p;
            p = __expf(fmaf(a0, zd.x, -m0)); s0 += p; w0 = fmaf(p, a0, w0);
            p = __expf(fmaf(b0, zd.y, -m1)); s1 += p; w1 = fmaf(p, b0, w1);
            p = __expf(fmaf(a1, zd.x, -m0)); s0 += p; w0 = fmaf(p, a1, w0);
            p = __expf(fmaf(b1, zd.y, -m1)); s1 += p; w1 = fmaf(p, b1, w1);
            p = __expf(fmaf(a2, zd.x, -m0)); s0 += p; w0 = fmaf(p, a2, w0);
            p = __expf(fmaf(b2, zd.y, -m1)); s1 += p; w1 = fmaf(p, b2, w1);
            p = __expf(fmaf(a3, zd.x, -m0)); s0 += p; w0 = fmaf(p, a3, w0);
            p = __expf(fmaf(b3, zd.y, -m1)); s1 += p; w1 = fmaf(p, b3, w1);
        }
        for (; j < cnt; ++j) {
            int sn = __builtin_amdgcn_readlane(es, j);
            unsigned v = *reinterpret_cast<const unsigned*>(z2 + (size_t)sn * DIM + lane * 2);
            union { unsigned u; _Float16 f[2]; } cv; cv.u = v;
            float zs0 = (float)cv.f[0], zs1 = (float)cv.f[1];
            float p0 = __expf(fmaf(zs0, zd.x, -m0));
            float p1 = __expf(fmaf(zs1, zd.y, -m1));
            s0 += p0; w0 = fmaf(p0, zs0, w0);
            s1 += p1; w1 = fmaf(p1, zs1, w1);
        }
    }
    float snv = snorm[node];
    float2 o;
    o.x = (s0 > 0.f) ? (w0 / s0) * snv : 0.f;
    o.y = (s1 > 0.f) ? (w1 / s1) * snv : 0.f;
    reinterpret_cast<float2*>(hout)[(size_t)node * 64 + lane] = o;
}

// ---------------- batch-norm statistics ----------------
__global__ __launch_bounds__(256) void reduce_kernel(const float* __restrict__ hout,
                                                     float* __restrict__ redbuf) {
    __shared__ float lsum[256], lsq[256];
    int tid = threadIdx.x;
    int c = tid & 127;
    int half = tid >> 7;
    int rbeg = blockIdx.x * 150;              // grid = 200 exact
    float s = 0.f, q = 0.f;
    for (int r = rbeg + half; r < rbeg + 150; r += 2) {
        float v = hout[(size_t)r * DIM + c];
        s += v; q += v * v;
    }
    lsum[tid] = s; lsq[tid] = q;
    __syncthreads();
    if (tid < 128) {
        s = lsum[tid] + lsum[tid + 128];
        q = lsq[tid] + lsq[tid + 128];
        atomicAdd(&redbuf[c], s);
        atomicAdd(&redbuf[DIM + c], q);
    }
}

// ---------------- fused BN-param + ELU + fp32 store (finalize folded in) ------
__global__ __launch_bounds__(256) void elu_kernel(const float* __restrict__ hout,
                                                  const float* __restrict__ redbuf,
                                                  const float* __restrict__ gamma,
                                                  const float* __restrict__ beta,
                                                  float* __restrict__ out) {
    int idx = (blockIdx.x * 256 + threadIdx.x) * 4;   // grid = 3750 exact
    int c = idx & 127;
    float4 v = reinterpret_cast<const float4*>(hout)[idx >> 2];
    float xs[4] = {v.x, v.y, v.z, v.w};
    float os[4];
    #pragma unroll
    for (int k = 0; k < 4; ++k) {
        float mu = redbuf[c + k] * (1.0f / N_NODES);
        float var = redbuf[DIM + c + k] * (1.0f / N_NODES) - mu * mu;
        float scale = gamma[c + k] * rsqrtf(var + EPSV);
        float shift = beta[c + k] - mu * scale;
        float y = xs[k] * scale + shift;
        os[k] = (y > 0.f) ? y : expm1f(y);
    }
    float4 o = {os[0], os[1], os[2], os[3]};
    reinterpret_cast<float4*>(out)[idx >> 2] = o;
}

extern "C" void kernel_launch(void* const* d_in, const int* in_sizes, int n_in,
                              void* d_out, int out_size, void* d_ws, size_t ws_size,
                              hipStream_t stream) {
    const float* h     = (const float*)d_in[0];
    const float* snorm = (const float*)d_in[1];
    const float* W     = (const float*)d_in[2];
    const float* gamma = (const float*)d_in[3];
    const float* beta  = (const float*)d_in[4];
    const int*   src   = (const int*)d_in[5];
    const int*   dst   = (const int*)d_in[6];
    float*       out   = (float*)d_out;

    char* ws = (char*)d_ws;
    float*          zbuf     = (float*)         (ws + 0);          // z, later hout (15,360,000 B)
    unsigned short* z2       = (unsigned short*)(ws + 15360000);   //  7,680,000 B (fp16 z)
    unsigned short* hh       = (unsigned short*)(ws + 23040000);   //  7,680,000 B
    unsigned short* hl       = (unsigned short*)(ws + 30720000);   //  7,680,000 B
    unsigned short* wh2      = (unsigned short*)(ws + 38400000);   //     32,768 B
    unsigned short* wl2      = (unsigned short*)(ws + 38432768);   //     32,768 B
    int*            counts   = (int*)           (ws + 38465536);   //    120,000 B
    int*            offsets  = (int*)           (ws + 38585536);   //    120,004 B
    int*            cursor   = (int*)           (ws + 38705552);   //    120,000 B
    int*            edge_src = (int*)           (ws + 38825552);   //  1,920,000 B
    float*          redbuf   = (float*)         (ws + 40745552);   //      1,024 B
    int*            zmax     = (int*)           (ws + 40746576);   //          4 B
    int*            partials = (int*)           (ws + 40746580);   //        472 B
    int*            ps       = (int*)           (ws + 40747052);   //        476 B

    convert_kernel<<<3766, 256, 0, stream>>>(h, W, hh, hl, wh2, wl2, counts, redbuf, zmax);
    count_kernel<<<(N_EDGES + 255) / 256, 256, 0, stream>>>(dst, counts);
    scan1_kernel<<<118, 256, 0, stream>>>(counts, offsets, partials);
    scan2_kernel<<<1, 64, 0, stream>>>(partials, ps);
    scan3_kernel<<<118, 256, 0, stream>>>(offsets, ps, cursor);
    fill_kernel<<<(N_EDGES + 255) / 256, 256, 0, stream>>>(src, dst, cursor, edge_src);
    gemm_kernel<<<235, 256, 0, stream>>>(hh, hl, wh2, wl2, zbuf, z2, zmax);
    node_kernel<<<N_NODES / 4, 256, 0, stream>>>(zbuf, z2, offsets, edge_src, snorm, zmax, zbuf);
    reduce_kernel<<<200, 256, 0, stream>>>(zbuf, redbuf);
    elu_kernel<<<(N_NODES * DIM) / 1024, 256, 0, stream>>>(zbuf, redbuf, gamma, beta, out);
}